// Round 6
// baseline (355.865 us; speedup 1.0000x reference)
//
#include <hip/hip_runtime.h>
#include <math.h>

#define Bn 4
#define Qn 300
#define WL 8
#define Hh 64
#define Ww 64
#define Dd 256
#define Mm 4

// ---------------- helpers ----------------
__device__ __forceinline__ float wave_reduce(float v) {
#pragma unroll
    for (int off = 32; off > 0; off >>= 1) v += __shfl_down(v, off, 64);
    return v;
}

// 512-thread block reduce (inactive threads must pass 0)
__device__ __forceinline__ float block_reduce512(float v, float* lds) {
    v = wave_reduce(v);
    int lane = threadIdx.x & 63, wv = threadIdx.x >> 6;
    if (lane == 0) lds[wv] = v;
    __syncthreads();
    float r = lds[0] + lds[1] + lds[2] + lds[3] + lds[4] + lds[5] + lds[6] + lds[7];
    __syncthreads();
    return r;
}

__device__ __forceinline__ float lo16(unsigned u) { return __uint_as_float(u << 16); }
__device__ __forceinline__ float hi16(unsigned u) { return __uint_as_float(u & 0xffff0000u); }

__device__ __forceinline__ unsigned bfp(float a, float b) {
    unsigned ua = __float_as_uint(a); ua = (ua + 0x7fffu + ((ua >> 16) & 1u)) >> 16;
    unsigned ub = __float_as_uint(b); ub = (ub + 0x7fffu + ((ub >> 16) & 1u)) >> 16;
    return ua | (ub << 16);
}

// ---------------- kernel 0: prep ----------------
// pack weights (uint4-group layout), transpose w_rel, transpose Wc
// pk layout per GEMM: group g (8 k's = 4 bf16-pairs), col c, pair p:
//   pk[(g*N + c)*4 + p] = bfp(W[(g*8+2p)*N + c], W[(g*8+2p+1)*N + c])
__global__ void __launch_bounds__(256) k_prep(const float* __restrict__ wp,
                                              const float* __restrict__ wf1,
                                              const float* __restrict__ wf2,
                                              const float* __restrict__ w_rel,
                                              const float* __restrict__ w_delta,
                                              const float* __restrict__ w_alpha,
                                              unsigned* __restrict__ pk,
                                              float* __restrict__ wrT,
                                              float* __restrict__ WcTg) {
    int bid = blockIdx.x, t = threadIdx.x;
    if (bid < 1152) {
        int i = bid * 256 + t;               // 0..294911
        if (i < 32768) {                     // pkP: K=256(g<32), N=256
            int p = i & 3, c = (i >> 2) & 255, g = i >> 10;
            pk[i] = bfp(wp[(g * 8 + 2 * p) * 256 + c], wp[(g * 8 + 2 * p + 1) * 256 + c]);
        } else if (i < 163840) {             // pkF1: K=256(g<32), N=1024
            int i2 = i - 32768;
            int p = i2 & 3, c = (i2 >> 2) & 1023, g = i2 >> 12;
            pk[i] = bfp(wf1[(g * 8 + 2 * p) * 1024 + c], wf1[(g * 8 + 2 * p + 1) * 1024 + c]);
        } else {                             // pkF2: K=1024(g<128), N=256
            int i3 = i - 163840;
            int p = i3 & 3, c = (i3 >> 2) & 255, g = i3 >> 10;
            pk[i] = bfp(wf2[(g * 8 + 2 * p) * 256 + c], wf2[(g * 8 + 2 * p + 1) * 256 + c]);
        }
    } else if (bid < 1216) {                 // wrT[col][k] = w_rel[k][col]
        int u = (bid - 1152) * 256 + t;      // 0..16383
        int col = u >> 6, k = u & 63;
        wrT[u] = w_rel[k * 256 + col];
    } else {                                 // WcTg[jj][k], jj<16, k<512
        int u = (bid - 1216) * 256 + t;      // 0..8191
        int jj = u >> 9, k = u & 511;
        WcTg[u] = (jj < 12) ? w_delta[k * 12 + jj] : w_alpha[k * 4 + (jj - 12)];
    }
}

// ---------------- kernel 1: FUSED LN1 + point params + gather ----------------
// one block per (b,q); 512 threads (8 waves)
__global__ void __launch_bounds__(512) k_fused(const float* __restrict__ q,
                                               const float* __restrict__ g1,
                                               const float* __restrict__ b1,
                                               const float* __restrict__ w_ref,
                                               const float* __restrict__ b_ref,
                                               const float* __restrict__ dsec,
                                               const float* __restrict__ wrT,
                                               const float* __restrict__ WcTg,
                                               const float* __restrict__ b_rel,
                                               const float* __restrict__ b_delta,
                                               const float* __restrict__ b_alpha,
                                               const unsigned char* __restrict__ mask,
                                               const float* __restrict__ feats,
                                               float* __restrict__ agg) {
    __shared__ float lds[8];
    __shared__ float sref[2];
    __shared__ float sqn[256];
    __shared__ float pe[8][64];
    __shared__ float relS[8][260];    // +4 pad
    __shared__ float qpart[8][16];
    __shared__ float rp[8][8][16];
    __shared__ float res[8][16];
    __shared__ unsigned recS[32 * 16];
    __shared__ float part[8][256];

    int bq = blockIdx.x, t = threadIdx.x;

    // ---- LN1 (256 data lanes; others contribute 0) ----
    float x = (t < 256) ? q[bq * Dd + t] : 0.f;
    float m = block_reduce512(x, lds) * (1.f / Dd);
    float dx = x - m;
    float v = block_reduce512((t < 256) ? dx * dx : 0.f, lds) * (1.f / Dd);
    float y = 0.f;
    if (t < 256) {
        y = dx * rsqrtf(v + 1e-5f) * g1[t] + b1[t];
        sqn[t] = y;
    }

    // ---- ref = sigmoid(qn @ w_ref + b_ref) ----
    float s0 = block_reduce512((t < 256) ? y * w_ref[t * 2 + 0] : 0.f, lds);
    float s1 = block_reduce512((t < 256) ? y * w_ref[t * 2 + 1] : 0.f, lds);
    if (t == 0) {
        sref[0] = 1.f / (1.f + expf(-(s0 + b_ref[0])));
        sref[1] = 1.f / (1.f + expf(-(s1 + b_ref[1])));
    }

    // ---- sinusoidal PE for all 8 windows ----
    if (t < 256) {
        int wl = t >> 5, i = t & 31;
        float f = expf(-logf(10000.f) * (float)i * (1.f / 32.f));
        float a = dsec[bq * WL + wl] * f;
        pe[wl][i] = sinf(a);
        pe[wl][i + 32] = cosf(a);
    }
    __syncthreads();

    // ---- rel_feat: thread (col, half) computes 4 windows; pe reads are broadcasts ----
    {
        int col = t & 255, half = t >> 8;
        float wr[64];
        const float4* w4 = (const float4*)&wrT[col * 64];
#pragma unroll
        for (int i = 0; i < 16; i++) {
            float4 vv = w4[i];
            wr[4 * i] = vv.x; wr[4 * i + 1] = vv.y; wr[4 * i + 2] = vv.z; wr[4 * i + 3] = vv.w;
        }
        float brl = b_rel[col];
#pragma unroll
        for (int w8 = 0; w8 < 4; w8++) {
            int wl = half * 4 + w8;
            const float4* p4 = (const float4*)&pe[wl][0];
            float r = brl;
#pragma unroll
            for (int k4 = 0; k4 < 16; k4++) {
                float4 p = p4[k4];
                r += p.x * wr[4 * k4] + p.y * wr[4 * k4 + 1]
                   + p.z * wr[4 * k4 + 2] + p.w * wr[4 * k4 + 3];
            }
            relS[wl][col] = r;
        }
    }
    __syncthreads();

    // ---- chunked dots: res[wl][jj] = b + sum_k psi[k]*Wc[k][jj] ----
    if (t < 256) {
        int chunk = t >> 4, jj = t & 15;
        float w[32];
        const float4* wg = (const float4*)&WcTg[jj * 512 + chunk * 32];
#pragma unroll
        for (int i = 0; i < 8; i++) {
            float4 vv = wg[i];
            w[4 * i] = vv.x; w[4 * i + 1] = vv.y; w[4 * i + 2] = vv.z; w[4 * i + 3] = vv.w;
        }
        if (chunk < 8) {
            const float4* a4 = (const float4*)&sqn[chunk * 32];
            float s = 0.f;
#pragma unroll
            for (int ii = 0; ii < 8; ii++) {
                int i = (ii + chunk) & 7;
                float4 a = a4[i];
                s += a.x * w[4 * i] + a.y * w[4 * i + 1] + a.z * w[4 * i + 2] + a.w * w[4 * i + 3];
            }
            qpart[chunk][jj] = s;
        } else {
            int ch = chunk - 8;
#pragma unroll
            for (int wl = 0; wl < WL; wl++) {
                const float4* a4 = (const float4*)&relS[wl][ch * 32];
                float s = 0.f;
#pragma unroll
                for (int ii = 0; ii < 8; ii++) {
                    int i = (ii + ch) & 7;
                    float4 a = a4[i];
                    s += a.x * w[4 * i] + a.y * w[4 * i + 1] + a.z * w[4 * i + 2] + a.w * w[4 * i + 3];
                }
                rp[wl][ch][jj] = s;
            }
        }
    }
    __syncthreads();
    if (t < 128) {
        int wl = t >> 4, jj = t & 15;
        float s = (jj < 12) ? b_delta[jj] : b_alpha[jj - 12];
#pragma unroll
        for (int c = 0; c < 8; c++) s += qpart[c][jj] + rp[wl][c][jj];
        res[wl][jj] = s;
    }
    __syncthreads();

    // ---- per-point records (into LDS) ----
    if (t < 32) {
        int wl = t >> 2, mm = t & 3;
        float l0 = res[wl][12], l1 = res[wl][13], l2 = res[wl][14], l3 = res[wl][15];
        float mx = fmaxf(fmaxf(l0, l1), fmaxf(l2, l3));
        float inv = 1.f / (expf(l0 - mx) + expf(l1 - mx) + expf(l2 - mx) + expf(l3 - mx));
        // -lam_sp*|dsec| shift is constant across M -> drops out of softmax
        float wgt = expf(res[wl][12 + mm] - mx) * inv;

        float cx = fminf(fmaxf(sref[0] + tanhf(res[wl][mm * 3 + 0]), 0.f), 1.f);
        float cy = fminf(fmaxf(sref[1] + tanhf(res[wl][mm * 3 + 1]), 0.f), 1.f);
        float tgt = (float)wl + tanhf(res[wl][mm * 3 + 2]);
        float t0f = fminf(fmaxf(floorf(tgt), 0.f), (float)(WL - 1));
        float t1f = fminf(t0f + 1.f, (float)(WL - 1));
        float alpha = tgt - t0f;
        float px = cx * (float)Ww - 0.5f, py = cy * (float)Hh - 0.5f;
        float fx = floorf(px), fy = floorf(py);
        float wx = px - fx, wy = py - fy;
        int X0 = (int)fminf(fmaxf(fx, 0.f), (float)(Ww - 1));
        int X1 = (int)fminf(fmaxf(fx + 1.f, 0.f), (float)(Ww - 1));
        int Y0 = (int)fminf(fmaxf(fy, 0.f), (float)(Hh - 1));
        int Y1 = (int)fminf(fmaxf(fy + 1.f, 0.f), (float)(Hh - 1));
        int T0 = (int)t0f, T1 = (int)t1f;

        float w00 = (1.f - wy) * (1.f - wx), w01 = (1.f - wy) * wx;
        float w10 = wy * (1.f - wx), w11 = wy * wx;
        float wt0 = wgt * (1.f - alpha), wt1 = wgt * alpha;

        int b = bq / Qn;
        int base0 = (b * WL + T0) * Hh;
        int base1 = (b * WL + T1) * Hh;
        int i00 = (base0 + Y0) * Ww + X0, i01 = (base0 + Y0) * Ww + X1;
        int i10 = (base0 + Y1) * Ww + X0, i11 = (base0 + Y1) * Ww + X1;
        int j00 = (base1 + Y0) * Ww + X0, j01 = (base1 + Y0) * Ww + X1;
        int j10 = (base1 + Y1) * Ww + X0, j11 = (base1 + Y1) * Ww + X1;

        unsigned* rec = &recS[t * 16];
        rec[0] = __float_as_uint(wt0 * w00 * (mask[i00] ? 0.f : 1.f));
        rec[1] = __float_as_uint(wt0 * w01 * (mask[i01] ? 0.f : 1.f));
        rec[2] = __float_as_uint(wt0 * w10 * (mask[i10] ? 0.f : 1.f));
        rec[3] = __float_as_uint(wt0 * w11 * (mask[i11] ? 0.f : 1.f));
        rec[4] = __float_as_uint(wt1 * w00 * (mask[j00] ? 0.f : 1.f));
        rec[5] = __float_as_uint(wt1 * w01 * (mask[j01] ? 0.f : 1.f));
        rec[6] = __float_as_uint(wt1 * w10 * (mask[j10] ? 0.f : 1.f));
        rec[7] = __float_as_uint(wt1 * w11 * (mask[j11] ? 0.f : 1.f));
        rec[8] = i00; rec[9] = i01; rec[10] = i10; rec[11] = i11;
        rec[12] = j00; rec[13] = j01; rec[14] = j10; rec[15] = j11;
    }
    __syncthreads();

    // ---- gather: wave j owns points 4j..4j+3; lane l -> channels 4l..4l+3 ----
    {
        int l = t & 63, j = t >> 6;
        const float4* f4 = (const float4*)feats;
        float4 acc = {0.f, 0.f, 0.f, 0.f};
#pragma unroll
        for (int p = 0; p < 4; p++) {
            const unsigned* rec = &recS[(j * 4 + p) * 16];
#pragma unroll
            for (int cn = 0; cn < 8; cn++) {
                float w = __uint_as_float(rec[cn]);
                size_t idx = rec[8 + cn];
                float4 vv = f4[idx * 64 + l];
                acc.x += w * vv.x; acc.y += w * vv.y; acc.z += w * vv.z; acc.w += w * vv.w;
            }
        }
        ((float4*)&part[j][0])[l] = acc;
    }
    __syncthreads();
    if (t < 256) {
        float s = part[0][t] + part[1][t] + part[2][t] + part[3][t]
                + part[4][t] + part[5][t] + part[6][t] + part[7][t];
        agg[(size_t)bq * Dd + t] = s;
    }
}

// ---------------- kernel 2: proj + residual + LN2 + FFN (+residual) ----------------
// 256 blocks x 1024 threads, 1 block/CU; all waves active; uint4 weight loads.
template<int R>
__device__ __forceinline__ void out_body(int row0,
        const float* __restrict__ q, const float* __restrict__ agg,
        const unsigned* __restrict__ pkP, const float* __restrict__ b_proj,
        const float* __restrict__ g2, const float* __restrict__ b2,
        const unsigned* __restrict__ pkF1, const float* __restrict__ b_ffn1,
        const unsigned* __restrict__ pkF2, const float* __restrict__ b_ffn2,
        float* __restrict__ out,
        float* sA, float* sO, float* sH, float* sF, float* sP, float* sRed) {
    int t = threadIdx.x;
    int c = t & 255, j = t >> 8;

    for (int u = t; u < 256 * R; u += 1024) {
        int r = u >> 8, cc = u & 255;
        sA[r * 256 + cc] = agg[(size_t)(row0 + r) * Dd + cc];
    }
    __syncthreads();

    // ---- proj: K-quarter j (groups j*8..j*8+7), col c ----
    {
        float acc[R];
#pragma unroll
        for (int r = 0; r < R; r++) acc[r] = 0.f;
#pragma unroll 2
        for (int gg = 0; gg < 8; gg++) {
            int g = j * 8 + gg;
            uint4 wv = *(const uint4*)&pkP[((unsigned)(g * 256 + c)) * 4];
            float w0 = lo16(wv.x), w1 = hi16(wv.x), w2 = lo16(wv.y), w3 = hi16(wv.y);
            float w4 = lo16(wv.z), w5 = hi16(wv.z), w6 = lo16(wv.w), w7 = hi16(wv.w);
#pragma unroll
            for (int r = 0; r < R; r++) {
                float4 ha = ((const float4*)&sA[r * 256])[g * 2];
                float4 hb = ((const float4*)&sA[r * 256])[g * 2 + 1];
                acc[r] += ha.x * w0 + ha.y * w1 + ha.z * w2 + ha.w * w3
                        + hb.x * w4 + hb.y * w5 + hb.z * w6 + hb.w * w7;
            }
        }
#pragma unroll
        for (int r = 0; r < R; r++) sP[(j * 5 + r) * 256 + c] = acc[r];
    }
    __syncthreads();

    // ---- combine + residual ----
    for (int u = t; u < 256 * R; u += 1024) {
        int r = u >> 8, cc = u & 255;
        float o = sP[(0 * 5 + r) * 256 + cc] + sP[(1 * 5 + r) * 256 + cc]
                + sP[(2 * 5 + r) * 256 + cc] + sP[(3 * 5 + r) * 256 + cc]
                + q[(size_t)(row0 + r) * Dd + cc] + b_proj[cc];
        sO[r * 256 + cc] = o;
    }
    __syncthreads();

    // ---- LN2: wave r reduces row r ----
    {
        int wv = t >> 6, l = t & 63;
        if (wv < R) {
            float4 v = ((const float4*)&sO[wv * 256])[l];
            float s = v.x + v.y + v.z + v.w;
            s = __shfl(wave_reduce(s), 0, 64);
            float mean = s * (1.f / 256.f);
            float d0 = v.x - mean, d1 = v.y - mean, d2 = v.z - mean, d3 = v.w - mean;
            float ss = d0 * d0 + d1 * d1 + d2 * d2 + d3 * d3;
            ss = __shfl(wave_reduce(ss), 0, 64);
            float rstd = rsqrtf(ss * (1.f / 256.f) + 1e-5f);
            if (l == 0) { sRed[wv * 2] = mean; sRed[wv * 2 + 1] = rstd; }
        }
    }
    __syncthreads();
    for (int u = t; u < 256 * R; u += 1024) {
        int r = u >> 8, cc = u & 255;
        sH[r * 256 + cc] = (sO[r * 256 + cc] - sRed[r * 2]) * sRed[r * 2 + 1] * g2[cc] + b2[cc];
    }
    __syncthreads();

    // ---- FFN1 + exact GELU: thread t = col t, full K=256 (32 groups) ----
    {
        float f[R];
#pragma unroll
        for (int r = 0; r < R; r++) f[r] = 0.f;
#pragma unroll 2
        for (int g = 0; g < 32; g++) {
            uint4 wv = *(const uint4*)&pkF1[((unsigned)(g * 1024 + t)) * 4];
            float w0 = lo16(wv.x), w1 = hi16(wv.x), w2 = lo16(wv.y), w3 = hi16(wv.y);
            float w4 = lo16(wv.z), w5 = hi16(wv.z), w6 = lo16(wv.w), w7 = hi16(wv.w);
#pragma unroll
            for (int r = 0; r < R; r++) {
                float4 ha = ((const float4*)&sH[r * 256])[g * 2];
                float4 hb = ((const float4*)&sH[r * 256])[g * 2 + 1];
                f[r] += ha.x * w0 + ha.y * w1 + ha.z * w2 + ha.w * w3
                      + hb.x * w4 + hb.y * w5 + hb.z * w6 + hb.w * w7;
            }
        }
        float bf = b_ffn1[t];
#pragma unroll
        for (int r = 0; r < R; r++) {
            float xx = f[r] + bf;
            sF[r * 1024 + t] = 0.5f * xx * (1.f + erff(xx * 0.70710678118654752f));
        }
    }
    __syncthreads();

    // ---- FFN2: K-quarter j (groups j*32..j*32+31), col c ----
    {
        float acc[R];
#pragma unroll
        for (int r = 0; r < R; r++) acc[r] = 0.f;
#pragma unroll 2
        for (int gg = 0; gg < 32; gg++) {
            int g = j * 32 + gg;
            uint4 wv = *(const uint4*)&pkF2[((unsigned)(g * 256 + c)) * 4];
            float w0 = lo16(wv.x), w1 = hi16(wv.x), w2 = lo16(wv.y), w3 = hi16(wv.y);
            float w4 = lo16(wv.z), w5 = hi16(wv.z), w6 = lo16(wv.w), w7 = hi16(wv.w);
#pragma unroll
            for (int r = 0; r < R; r++) {
                float4 ha = ((const float4*)&sF[r * 1024])[g * 2];
                float4 hb = ((const float4*)&sF[r * 1024])[g * 2 + 1];
                acc[r] += ha.x * w0 + ha.y * w1 + ha.z * w2 + ha.w * w3
                        + hb.x * w4 + hb.y * w5 + hb.z * w6 + hb.w * w7;
            }
        }
#pragma unroll
        for (int r = 0; r < R; r++) sP[(j * 5 + r) * 256 + c] = acc[r];
    }
    __syncthreads();

    for (int u = t; u < 256 * R; u += 1024) {
        int r = u >> 8, cc = u & 255;
        float s = sP[(0 * 5 + r) * 256 + cc] + sP[(1 * 5 + r) * 256 + cc]
                + sP[(2 * 5 + r) * 256 + cc] + sP[(3 * 5 + r) * 256 + cc];
        out[(size_t)(row0 + r) * Dd + cc] = sO[r * 256 + cc] + s + b_ffn2[cc];
    }
}

__global__ void __launch_bounds__(1024) k_out(const float* __restrict__ q,
                                              const float* __restrict__ agg,
                                              const unsigned* __restrict__ pkP,
                                              const float* __restrict__ b_proj,
                                              const float* __restrict__ g2,
                                              const float* __restrict__ b2,
                                              const unsigned* __restrict__ pkF1,
                                              const float* __restrict__ b_ffn1,
                                              const unsigned* __restrict__ pkF2,
                                              const float* __restrict__ b_ffn2,
                                              float* __restrict__ out) {
    __shared__ float sA[5 * 256];
    __shared__ float sO[5 * 256];
    __shared__ float sH[5 * 256];
    __shared__ float sF[5 * 1024];
    __shared__ float sP[4 * 5 * 256];
    __shared__ float sRed[16];
    __shared__ float pad[8192];   // inflate LDS -> exactly 1 block/CU (perfect balance)
    if (b_ffn2 == nullptr) pad[threadIdx.x] = 0.f;   // keeps pad alive; never executes

    int bid = blockIdx.x;
    if (bid < 176) {
        out_body<5>(bid * 5, q, agg, pkP, b_proj, g2, b2, pkF1, b_ffn1, pkF2, b_ffn2,
                    out, sA, sO, sH, sF, sP, sRed);
    } else {
        out_body<4>(880 + (bid - 176) * 4, q, agg, pkP, b_proj, g2, b2, pkF1, b_ffn1,
                    pkF2, b_ffn2, out, sA, sO, sH, sF, sP, sRed);
    }
}

// ---------------- launcher ----------------
extern "C" void kernel_launch(void* const* d_in, const int* in_sizes, int n_in,
                              void* d_out, int out_size, void* d_ws, size_t ws_size,
                              hipStream_t stream) {
    const float* q        = (const float*)d_in[0];
    const float* kv_feats = (const float*)d_in[1];
    const unsigned char* kv_mask = (const unsigned char*)d_in[2];
    const float* delta_sec= (const float*)d_in[3];
    const float* w_ref    = (const float*)d_in[4];
    const float* b_ref    = (const float*)d_in[5];
    const float* w_delta  = (const float*)d_in[6];
    const float* b_delta  = (const float*)d_in[7];
    const float* w_alpha  = (const float*)d_in[8];
    const float* b_alpha  = (const float*)d_in[9];
    // d_in[10] = lam: softmax shift-invariance makes it a no-op
    const float* w_proj   = (const float*)d_in[11];
    const float* b_proj   = (const float*)d_in[12];
    const float* ln1_g    = (const float*)d_in[13];
    const float* ln1_b    = (const float*)d_in[14];
    const float* ln2_g    = (const float*)d_in[15];
    const float* ln2_b    = (const float*)d_in[16];
    const float* w_ffn1   = (const float*)d_in[17];
    const float* b_ffn1   = (const float*)d_in[18];
    const float* w_ffn2   = (const float*)d_in[19];
    const float* b_ffn2   = (const float*)d_in[20];
    const float* w_rel    = (const float*)d_in[21];
    const float* b_rel    = (const float*)d_in[22];
    float* out = (float*)d_out;

    unsigned* pk   = (unsigned*)d_ws;                  // 294912 uints
    unsigned* pkP  = pk;
    unsigned* pkF1 = pk + 32768;
    unsigned* pkF2 = pk + 163840;
    float*    wrT  = (float*)(pk + 294912);            // 16384 floats
    float*    WcTg = wrT + 16384;                      // 8192 floats
    float*    agg  = WcTg + 8192;                      // 307200 floats

    const int BQ = Bn * Qn;                            // 1200
    k_prep<<<dim3(1248), dim3(256), 0, stream>>>(w_proj, w_ffn1, w_ffn2, w_rel,
                                                 w_delta, w_alpha, pk, wrT, WcTg);
    k_fused<<<dim3(BQ), dim3(512), 0, stream>>>(q, ln1_g, ln1_b, w_ref, b_ref, delta_sec,
                                                wrT, WcTg, b_rel, b_delta, b_alpha,
                                                kv_mask, kv_feats, agg);
    k_out<<<dim3(256), dim3(1024), 0, stream>>>(q, agg, pkP, b_proj, ln2_g, ln2_b,
                                                pkF1, b_ffn1, pkF2, b_ffn2, out);
}

// Round 7
// 300.023 us; speedup vs baseline: 1.1861x; 1.1861x over previous
//
#include <hip/hip_runtime.h>
#include <math.h>

#define Bn 4
#define Qn 300
#define WL 8
#define Hh 64
#define Ww 64
#define Dd 256
#define Mm 4

// ---------------- helpers ----------------
__device__ __forceinline__ float wave_reduce(float v) {
#pragma unroll
    for (int off = 32; off > 0; off >>= 1) v += __shfl_down(v, off, 64);
    return v;
}

__device__ __forceinline__ float block_reduce256(float v, float* lds) {
    v = wave_reduce(v);
    int lane = threadIdx.x & 63, wv = threadIdx.x >> 6;
    if (lane == 0) lds[wv] = v;
    __syncthreads();
    float r = lds[0] + lds[1] + lds[2] + lds[3];
    __syncthreads();
    return r;
}

__device__ __forceinline__ float lo16(unsigned u) { return __uint_as_float(u << 16); }
__device__ __forceinline__ float hi16(unsigned u) { return __uint_as_float(u & 0xffff0000u); }

__device__ __forceinline__ unsigned bfp(float a, float b) {
    unsigned ua = __float_as_uint(a); ua = (ua + 0x7fffu + ((ua >> 16) & 1u)) >> 16;
    unsigned ub = __float_as_uint(b); ub = (ub + 0x7fffu + ((ub >> 16) & 1u)) >> 16;
    return ua | (ub << 16);
}

// ---------------- kernel 1: merged weight-pack + (LN1 + point params) ----------------
// blocks 0..1151: pack weights to bf16 pairs, uint4-group layout:
//   pk[(g*N + c)*4 + p] = bfp(W[(g*8+2p)*N + c], W[(g*8+2p+1)*N + c])
// blocks 1152..2351: per-(b,q) LN1 + point params + mask-folded gather records
__global__ void __launch_bounds__(256) k_mid(const float* __restrict__ wp,
                                             const float* __restrict__ wf1,
                                             const float* __restrict__ wf2,
                                             unsigned* __restrict__ pk,
                                             const float* __restrict__ q,
                                             const float* __restrict__ g1,
                                             const float* __restrict__ b1,
                                             const float* __restrict__ w_ref,
                                             const float* __restrict__ b_ref,
                                             const float* __restrict__ dsec,
                                             const float* __restrict__ w_rel,
                                             const float* __restrict__ b_rel,
                                             const float* __restrict__ w_delta,
                                             const float* __restrict__ b_delta,
                                             const float* __restrict__ w_alpha,
                                             const float* __restrict__ b_alpha,
                                             const unsigned char* __restrict__ mask,
                                             unsigned* __restrict__ prm2) {
    __shared__ float lds[4];
    __shared__ float sref[2];
    __shared__ float sqn[256];
    __shared__ float pe[8][64];
    __shared__ float rel[8][260];     // +4 pad: 16B-aligned float4 rows
    __shared__ float WcT[16 * 516];   // WcT[j][k], row stride 516
    __shared__ float res[8][16];

    int bid = blockIdx.x, t = threadIdx.x;

    if (bid < 1152) {
        // ---------------- weight packing path ----------------
        int i = bid * 256 + t;               // 0..294911
        if (i < 32768) {                     // pkP: K=256 (g<32), N=256
            int p = i & 3, c = (i >> 2) & 255, g = i >> 10;
            pk[i] = bfp(wp[(g * 8 + 2 * p) * 256 + c], wp[(g * 8 + 2 * p + 1) * 256 + c]);
        } else if (i < 163840) {             // pkF1: K=256 (g<32), N=1024
            int i2 = i - 32768;
            int p = i2 & 3, c = (i2 >> 2) & 1023, g = i2 >> 12;
            pk[i] = bfp(wf1[(g * 8 + 2 * p) * 1024 + c], wf1[(g * 8 + 2 * p + 1) * 1024 + c]);
        } else {                             // pkF2: K=1024 (g<128), N=256
            int i3 = i - 163840;
            int p = i3 & 3, c = (i3 >> 2) & 255, g = i3 >> 10;
            pk[i] = bfp(wf2[(g * 8 + 2 * p) * 256 + c], wf2[(g * 8 + 2 * p + 1) * 256 + c]);
        }
        return;
    }

    int bq = bid - 1152;

    // ---- LN1 ----
    float x = q[bq * Dd + t];
    float m = block_reduce256(x, lds) * (1.f / Dd);
    float dx = x - m;
    float v = block_reduce256(dx * dx, lds) * (1.f / Dd);
    float y = dx * rsqrtf(v + 1e-5f) * g1[t] + b1[t];
    sqn[t] = y;

    // ---- ref = sigmoid(qn @ w_ref + b_ref) ----
    float s0 = block_reduce256(y * w_ref[t * 2 + 0], lds);
    float s1 = block_reduce256(y * w_ref[t * 2 + 1], lds);
    if (t == 0) {
        sref[0] = 1.f / (1.f + expf(-(s0 + b_ref[0])));
        sref[1] = 1.f / (1.f + expf(-(s1 + b_ref[1])));
    }

    // ---- sinusoidal PE for all 8 windows ----
    {
        int wl = t >> 5, i = t & 31;
        float f = expf(-logf(10000.f) * (float)i * (1.f / 32.f));
        float a = dsec[bq * WL + wl] * f;
        pe[wl][i] = sinf(a);
        pe[wl][i + 32] = cosf(a);
    }

    // ---- stage combined delta/alpha weights into LDS (transposed) ----
    for (int u = t; u < 512 * 16; u += 256) {
        int k = u >> 4, jj = u & 15;
        float w = (jj < 12) ? w_delta[k * 12 + jj] : w_alpha[k * 4 + (jj - 12)];
        WcT[jj * 516 + k] = w;
    }

    // ---- w_rel column t in registers ----
    float wr[64];
#pragma unroll
    for (int k = 0; k < 64; k++) wr[k] = w_rel[k * Dd + t];
    __syncthreads();

    // ---- rel_feat per window (pe via float4 broadcast reads) ----
    float brl = b_rel[t];
    for (int wl = 0; wl < WL; wl++) {
        const float4* p4 = (const float4*)&pe[wl][0];
        float r = brl;
#pragma unroll
        for (int k4 = 0; k4 < 16; k4++) {
            float4 p = p4[k4];
            r += p.x * wr[4 * k4] + p.y * wr[4 * k4 + 1]
               + p.z * wr[4 * k4 + 2] + p.w * wr[4 * k4 + 3];
        }
        rel[wl][t] = r;
    }
    __syncthreads();

    // ---- 16 dot products per window ----
    if (t < 128) {
        int wl = t >> 4, jj = t & 15;
        const float4* wrow = (const float4*)&WcT[jj * 516];
        const float4* qrow = (const float4*)sqn;
        const float4* rrow = (const float4*)&rel[wl][0];
        float s = 0.f;
#pragma unroll 8
        for (int k4 = 0; k4 < 64; k4++) {
            float4 a = qrow[k4], w = wrow[k4];
            s += a.x * w.x + a.y * w.y + a.z * w.z + a.w * w.w;
        }
#pragma unroll 8
        for (int k4 = 0; k4 < 64; k4++) {
            float4 a = rrow[k4], w = wrow[64 + k4];
            s += a.x * w.x + a.y * w.y + a.z * w.z + a.w * w.w;
        }
        s += (jj < 12) ? b_delta[jj] : b_alpha[jj - 12];
        res[wl][jj] = s;
    }
    __syncthreads();

    // ---- per-point records ----
    if (t < 32) {
        int wl = t >> 2, mm = t & 3;
        float l0 = res[wl][12], l1 = res[wl][13], l2 = res[wl][14], l3 = res[wl][15];
        float mx = fmaxf(fmaxf(l0, l1), fmaxf(l2, l3));
        float inv = 1.f / (expf(l0 - mx) + expf(l1 - mx) + expf(l2 - mx) + expf(l3 - mx));
        // -lam_sp*|dsec| shift is constant across M -> drops out of softmax
        float wgt = expf(res[wl][12 + mm] - mx) * inv;

        float cx = fminf(fmaxf(sref[0] + tanhf(res[wl][mm * 3 + 0]), 0.f), 1.f);
        float cy = fminf(fmaxf(sref[1] + tanhf(res[wl][mm * 3 + 1]), 0.f), 1.f);
        float tgt = (float)wl + tanhf(res[wl][mm * 3 + 2]);
        float t0f = fminf(fmaxf(floorf(tgt), 0.f), (float)(WL - 1));
        float t1f = fminf(t0f + 1.f, (float)(WL - 1));
        float alpha = tgt - t0f;
        float px = cx * (float)Ww - 0.5f, py = cy * (float)Hh - 0.5f;
        float fx = floorf(px), fy = floorf(py);
        float wx = px - fx, wy = py - fy;
        int X0 = (int)fminf(fmaxf(fx, 0.f), (float)(Ww - 1));
        int X1 = (int)fminf(fmaxf(fx + 1.f, 0.f), (float)(Ww - 1));
        int Y0 = (int)fminf(fmaxf(fy, 0.f), (float)(Hh - 1));
        int Y1 = (int)fminf(fmaxf(fy + 1.f, 0.f), (float)(Hh - 1));
        int T0 = (int)t0f, T1 = (int)t1f;

        float w00 = (1.f - wy) * (1.f - wx), w01 = (1.f - wy) * wx;
        float w10 = wy * (1.f - wx), w11 = wy * wx;
        float wt0 = wgt * (1.f - alpha), wt1 = wgt * alpha;

        int b = bq / Qn;
        int base0 = (b * WL + T0) * Hh;
        int base1 = (b * WL + T1) * Hh;
        int i00 = (base0 + Y0) * Ww + X0, i01 = (base0 + Y0) * Ww + X1;
        int i10 = (base0 + Y1) * Ww + X0, i11 = (base0 + Y1) * Ww + X1;
        int j00 = (base1 + Y0) * Ww + X0, j01 = (base1 + Y0) * Ww + X1;
        int j10 = (base1 + Y1) * Ww + X0, j11 = (base1 + Y1) * Ww + X1;

        unsigned* rec = prm2 + (unsigned)(bq * 32 + t) * 16;
        rec[0] = __float_as_uint(wt0 * w00 * (mask[i00] ? 0.f : 1.f));
        rec[1] = __float_as_uint(wt0 * w01 * (mask[i01] ? 0.f : 1.f));
        rec[2] = __float_as_uint(wt0 * w10 * (mask[i10] ? 0.f : 1.f));
        rec[3] = __float_as_uint(wt0 * w11 * (mask[i11] ? 0.f : 1.f));
        rec[4] = __float_as_uint(wt1 * w00 * (mask[j00] ? 0.f : 1.f));
        rec[5] = __float_as_uint(wt1 * w01 * (mask[j01] ? 0.f : 1.f));
        rec[6] = __float_as_uint(wt1 * w10 * (mask[j10] ? 0.f : 1.f));
        rec[7] = __float_as_uint(wt1 * w11 * (mask[j11] ? 0.f : 1.f));
        rec[8] = i00; rec[9] = i01; rec[10] = i10; rec[11] = i11;
        rec[12] = j00; rec[13] = j01; rec[14] = j10; rec[15] = j11;
    }
}

// ---------------- kernel 2: gather + weighted aggregation ----------------
// one block per (b,q); wave j owns points 4j..4j+3; lane l -> channels 4l..4l+3
__global__ void __launch_bounds__(512) k_gather(const float* __restrict__ feats,
                                                const unsigned* __restrict__ prm2,
                                                float* __restrict__ agg) {
    __shared__ unsigned P[32 * 16];
    __shared__ float part[8][256];
    int bq = blockIdx.x, t = threadIdx.x;
    int l = t & 63, j = t >> 6;
    P[t] = prm2[(unsigned)bq * 512 + t];
    __syncthreads();
    const float4* f4 = (const float4*)feats;
    float4 acc = {0.f, 0.f, 0.f, 0.f};
#pragma unroll
    for (int p = 0; p < 4; p++) {
        const unsigned* rec = &P[(j * 4 + p) * 16];
#pragma unroll
        for (int cn = 0; cn < 8; cn++) {
            float w = __uint_as_float(rec[cn]);
            size_t idx = rec[8 + cn];
            float4 v = f4[idx * 64 + l];
            acc.x += w * v.x; acc.y += w * v.y; acc.z += w * v.z; acc.w += w * v.w;
        }
    }
    ((float4*)&part[j][0])[l] = acc;
    __syncthreads();
    if (t < 256) {
        float s = part[0][t] + part[1][t] + part[2][t] + part[3][t]
                + part[4][t] + part[5][t] + part[6][t] + part[7][t];
        agg[(size_t)bq * Dd + t] = s;
    }
}

// ---------------- kernel 3: proj + residual + LN2 + FFN (+residual) ----------------
// 256 blocks x 1024 threads, 1 block/CU; all waves active; uint4 weight loads.
template<int R>
__device__ __forceinline__ void out_body(int row0,
        const float* __restrict__ q, const float* __restrict__ agg,
        const unsigned* __restrict__ pkP, const float* __restrict__ b_proj,
        const float* __restrict__ g2, const float* __restrict__ b2,
        const unsigned* __restrict__ pkF1, const float* __restrict__ b_ffn1,
        const unsigned* __restrict__ pkF2, const float* __restrict__ b_ffn2,
        float* __restrict__ out,
        float* sA, float* sO, float* sH, float* sF, float* sP, float* sRed) {
    int t = threadIdx.x;
    int c = t & 255, j = t >> 8;

    for (int u = t; u < 256 * R; u += 1024) {
        int r = u >> 8, cc = u & 255;
        sA[r * 256 + cc] = agg[(size_t)(row0 + r) * Dd + cc];
    }
    __syncthreads();

    // ---- proj: K-quarter j (groups j*8..j*8+7), col c ----
    {
        float acc[R];
#pragma unroll
        for (int r = 0; r < R; r++) acc[r] = 0.f;
#pragma unroll 2
        for (int gg = 0; gg < 8; gg++) {
            int g = j * 8 + gg;
            uint4 wv = *(const uint4*)&pkP[((unsigned)(g * 256 + c)) * 4];
            float w0 = lo16(wv.x), w1 = hi16(wv.x), w2 = lo16(wv.y), w3 = hi16(wv.y);
            float w4 = lo16(wv.z), w5 = hi16(wv.z), w6 = lo16(wv.w), w7 = hi16(wv.w);
#pragma unroll
            for (int r = 0; r < R; r++) {
                float4 ha = ((const float4*)&sA[r * 256])[g * 2];
                float4 hb = ((const float4*)&sA[r * 256])[g * 2 + 1];
                acc[r] += ha.x * w0 + ha.y * w1 + ha.z * w2 + ha.w * w3
                        + hb.x * w4 + hb.y * w5 + hb.z * w6 + hb.w * w7;
            }
        }
#pragma unroll
        for (int r = 0; r < R; r++) sP[(j * 5 + r) * 256 + c] = acc[r];
    }
    __syncthreads();

    // ---- combine + residual ----
    for (int u = t; u < 256 * R; u += 1024) {
        int r = u >> 8, cc = u & 255;
        float o = sP[(0 * 5 + r) * 256 + cc] + sP[(1 * 5 + r) * 256 + cc]
                + sP[(2 * 5 + r) * 256 + cc] + sP[(3 * 5 + r) * 256 + cc]
                + q[(size_t)(row0 + r) * Dd + cc] + b_proj[cc];
        sO[r * 256 + cc] = o;
    }
    __syncthreads();

    // ---- LN2: wave r reduces row r ----
    {
        int wv = t >> 6, l = t & 63;
        if (wv < R) {
            float4 v = ((const float4*)&sO[wv * 256])[l];
            float s = v.x + v.y + v.z + v.w;
            s = __shfl(wave_reduce(s), 0, 64);
            float mean = s * (1.f / 256.f);
            float d0 = v.x - mean, d1 = v.y - mean, d2 = v.z - mean, d3 = v.w - mean;
            float ss = d0 * d0 + d1 * d1 + d2 * d2 + d3 * d3;
            ss = __shfl(wave_reduce(ss), 0, 64);
            float rstd = rsqrtf(ss * (1.f / 256.f) + 1e-5f);
            if (l == 0) { sRed[wv * 2] = mean; sRed[wv * 2 + 1] = rstd; }
        }
    }
    __syncthreads();
    for (int u = t; u < 256 * R; u += 1024) {
        int r = u >> 8, cc = u & 255;
        sH[r * 256 + cc] = (sO[r * 256 + cc] - sRed[r * 2]) * sRed[r * 2 + 1] * g2[cc] + b2[cc];
    }
    __syncthreads();

    // ---- FFN1 + exact GELU: thread t = col t, full K=256 (32 groups) ----
    {
        float f[R];
#pragma unroll
        for (int r = 0; r < R; r++) f[r] = 0.f;
#pragma unroll 2
        for (int g = 0; g < 32; g++) {
            uint4 wv = *(const uint4*)&pkF1[((unsigned)(g * 1024 + t)) * 4];
            float w0 = lo16(wv.x), w1 = hi16(wv.x), w2 = lo16(wv.y), w3 = hi16(wv.y);
            float w4 = lo16(wv.z), w5 = hi16(wv.z), w6 = lo16(wv.w), w7 = hi16(wv.w);
#pragma unroll
            for (int r = 0; r < R; r++) {
                float4 ha = ((const float4*)&sH[r * 256])[g * 2];
                float4 hb = ((const float4*)&sH[r * 256])[g * 2 + 1];
                f[r] += ha.x * w0 + ha.y * w1 + ha.z * w2 + ha.w * w3
                      + hb.x * w4 + hb.y * w5 + hb.z * w6 + hb.w * w7;
            }
        }
        float bf = b_ffn1[t];
#pragma unroll
        for (int r = 0; r < R; r++) {
            float xx = f[r] + bf;
            sF[r * 1024 + t] = 0.5f * xx * (1.f + erff(xx * 0.70710678118654752f));
        }
    }
    __syncthreads();

    // ---- FFN2: K-quarter j (groups j*32..j*32+31), col c ----
    {
        float acc[R];
#pragma unroll
        for (int r = 0; r < R; r++) acc[r] = 0.f;
#pragma unroll 2
        for (int gg = 0; gg < 32; gg++) {
            int g = j * 32 + gg;
            uint4 wv = *(const uint4*)&pkF2[((unsigned)(g * 256 + c)) * 4];
            float w0 = lo16(wv.x), w1 = hi16(wv.x), w2 = lo16(wv.y), w3 = hi16(wv.y);
            float w4 = lo16(wv.z), w5 = hi16(wv.z), w6 = lo16(wv.w), w7 = hi16(wv.w);
#pragma unroll
            for (int r = 0; r < R; r++) {
                float4 ha = ((const float4*)&sF[r * 1024])[g * 2];
                float4 hb = ((const float4*)&sF[r * 1024])[g * 2 + 1];
                acc[r] += ha.x * w0 + ha.y * w1 + ha.z * w2 + ha.w * w3
                        + hb.x * w4 + hb.y * w5 + hb.z * w6 + hb.w * w7;
            }
        }
#pragma unroll
        for (int r = 0; r < R; r++) sP[(j * 5 + r) * 256 + c] = acc[r];
    }
    __syncthreads();

    for (int u = t; u < 256 * R; u += 1024) {
        int r = u >> 8, cc = u & 255;
        float s = sP[(0 * 5 + r) * 256 + cc] + sP[(1 * 5 + r) * 256 + cc]
                + sP[(2 * 5 + r) * 256 + cc] + sP[(3 * 5 + r) * 256 + cc];
        out[(size_t)(row0 + r) * Dd + cc] = sO[r * 256 + cc] + s + b_ffn2[cc];
    }
}

__global__ void __launch_bounds__(1024) k_out(const float* __restrict__ q,
                                              const float* __restrict__ agg,
                                              const unsigned* __restrict__ pkP,
                                              const float* __restrict__ b_proj,
                                              const float* __restrict__ g2,
                                              const float* __restrict__ b2,
                                              const unsigned* __restrict__ pkF1,
                                              const float* __restrict__ b_ffn1,
                                              const unsigned* __restrict__ pkF2,
                                              const float* __restrict__ b_ffn2,
                                              float* __restrict__ out) {
    __shared__ float sA[5 * 256];
    __shared__ float sO[5 * 256];
    __shared__ float sH[5 * 256];
    __shared__ float sF[5 * 1024];
    __shared__ float sP[4 * 5 * 256];
    __shared__ float sRed[16];
    __shared__ float pad[8192];   // inflate LDS -> exactly 1 block/CU (perfect balance)
    if (b_ffn2 == nullptr) pad[threadIdx.x] = 0.f;   // keeps pad alive; never executes

    int bid = blockIdx.x;
    if (bid < 176) {
        out_body<5>(bid * 5, q, agg, pkP, b_proj, g2, b2, pkF1, b_ffn1, pkF2, b_ffn2,
                    out, sA, sO, sH, sF, sP, sRed);
    } else {
        out_body<4>(880 + (bid - 176) * 4, q, agg, pkP, b_proj, g2, b2, pkF1, b_ffn1,
                    pkF2, b_ffn2, out, sA, sO, sH, sF, sP, sRed);
    }
}

// ---------------- launcher ----------------
extern "C" void kernel_launch(void* const* d_in, const int* in_sizes, int n_in,
                              void* d_out, int out_size, void* d_ws, size_t ws_size,
                              hipStream_t stream) {
    const float* q        = (const float*)d_in[0];
    const float* kv_feats = (const float*)d_in[1];
    const unsigned char* kv_mask = (const unsigned char*)d_in[2];
    const float* delta_sec= (const float*)d_in[3];
    const float* w_ref    = (const float*)d_in[4];
    const float* b_ref    = (const float*)d_in[5];
    const float* w_delta  = (const float*)d_in[6];
    const float* b_delta  = (const float*)d_in[7];
    const float* w_alpha  = (const float*)d_in[8];
    const float* b_alpha  = (const float*)d_in[9];
    // d_in[10] = lam: softmax shift-invariance makes it a no-op
    const float* w_proj   = (const float*)d_in[11];
    const float* b_proj   = (const float*)d_in[12];
    const float* ln1_g    = (const float*)d_in[13];
    const float* ln1_b    = (const float*)d_in[14];
    const float* ln2_g    = (const float*)d_in[15];
    const float* ln2_b    = (const float*)d_in[16];
    const float* w_ffn1   = (const float*)d_in[17];
    const float* b_ffn1   = (const float*)d_in[18];
    const float* w_ffn2   = (const float*)d_in[19];
    const float* b_ffn2   = (const float*)d_in[20];
    const float* w_rel    = (const float*)d_in[21];
    const float* b_rel    = (const float*)d_in[22];
    float* out = (float*)d_out;

    unsigned* pk   = (unsigned*)d_ws;                  // 294912 uints
    unsigned* pkP  = pk;
    unsigned* pkF1 = pk + 32768;
    unsigned* pkF2 = pk + 163840;
    unsigned* prm2 = pk + 294912;                      // 614400 uints
    float*    agg  = (float*)(prm2 + 614400);          // 307200 floats

    const int BQ = Bn * Qn;                            // 1200
    k_mid<<<dim3(1152 + BQ), dim3(256), 0, stream>>>(w_proj, w_ffn1, w_ffn2, pk,
                                                     q, ln1_g, ln1_b, w_ref, b_ref,
                                                     delta_sec, w_rel, b_rel,
                                                     w_delta, b_delta, w_alpha, b_alpha,
                                                     kv_mask, prm2);
    k_gather<<<dim3(BQ), dim3(512), 0, stream>>>(kv_feats, prm2, agg);
    k_out<<<dim3(256), dim3(1024), 0, stream>>>(q, agg, pkP, b_proj, ln2_g, ln2_b,
                                                pkF1, b_ffn1, pkF2, b_ffn2, out);
}